// Round 9
// baseline (878.764 us; speedup 1.0000x reference)
//
#include <hip/hip_runtime.h>

#define NB 16
#define HH 256
#define WW 256
#define NPIX (HH*WW)

typedef _Float16 f16;
typedef _Float16 f16x8 __attribute__((ext_vector_type(8)));
typedef float f32x4 __attribute__((ext_vector_type(4)));

// slotted+swizzled f16 LDS tile [P][64]: slot (16B, 8 f16) index XOR'd with p&7
__device__ __forceinline__ int swzoff(int p, int c) {
    return p * 64 + ((((c >> 3) ^ (p & 7)) << 3) | (c & 7));
}

// ---------------------------------------------------------------------------
// prepack: all weights -> f16 packed.
// pA1/pA2 [64][32] k=tap(9,pad32); pWa [64][32] k=cin*9+tap(18,pad32);
// pBs1/pBs2 [16][64] tap-shifted conv1b: row=tap(9 used), col=cin;
// pWb [64][576] k=tap*64+cin; pWc [96][576] rows81-95 zero.
// ---------------------------------------------------------------------------
__global__ __launch_bounds__(256) void prepack_kernel(
    const float* __restrict__ w1a, const float* __restrict__ w2a,
    const float* __restrict__ w1b, const float* __restrict__ w2b,
    const float* __restrict__ wfa, const float* __restrict__ wfb,
    const float* __restrict__ wfc,
    f16* __restrict__ pA1, f16* __restrict__ pA2, f16* __restrict__ pWa,
    f16* __restrict__ pBs1, f16* __restrict__ pBs2,
    f16* __restrict__ pWb, f16* __restrict__ pWc)
{
    int i = blockIdx.x * 256 + threadIdx.x;
    if (i < 2048) {
        int c = i >> 5, k = i & 31;
        pA1[i] = (f16)(k < 9 ? w1a[c * 9 + k] : 0.f);
        pA2[i] = (f16)(k < 9 ? w2a[c * 9 + k] : 0.f);
        pWa[i] = (f16)(k < 18 ? wfa[c * 18 + k] : 0.f);
    }
    if (i < 1024) {
        int r = i >> 6, cin = i & 63;   // row = tap, col = cin
        pBs1[i] = (f16)(r < 9 ? w1b[cin * 9 + r] : 0.f);
        pBs2[i] = (f16)(r < 9 ? w2b[cin * 9 + r] : 0.f);
    }
    if (i < 36864) {
        int c = i / 576, k = i % 576;
        int tap = k >> 6, cin = k & 63;
        pWb[i] = (f16)wfb[(c * 64 + cin) * 9 + tap];
    }
    if (i < 55296) {
        int r = i / 576, k = i % 576;
        int tap = k >> 6, cin = k & 63;
        pWc[i] = (f16)(r < 81 ? wfc[(r * 64 + cin) * 9 + tap] : 0.f);
    }
}

// ---------------------------------------------------------------------------
// K1: branch -> feat.  blockIdx.z = b*2+br.
// conv1a via MFMA (K=9 pad 32) -> hid 18x18x64 in LDS (swz).
// conv1b via TAP-SHIFTED MFMA: part[tap][q] = sum_cin w[cin][tap]*hid[q][cin],
// then out = 9-term LDS sum.
// ---------------------------------------------------------------------------
__global__ __launch_bounds__(256, 3) void k1_branch(
    const float* __restrict__ x, const float* __restrict__ g,
    const float* __restrict__ b1a, const float* __restrict__ b2a,
    const float* __restrict__ b1b, const float* __restrict__ b2b,
    const f16* __restrict__ pA1, const f16* __restrict__ pA2,
    const f16* __restrict__ pBs1, const f16* __restrict__ pBs2,
    float* __restrict__ feat)
{
    __shared__ f16 xt[400];       // 20x20 input tile
    __shared__ f16 hid[20736];    // [324][64] swz
    __shared__ f16 part[9 * 328]; // conv1b tap partials over 18x18 region
    __shared__ float bA[64];

    const int tid = threadIdx.x;
    const int wid = tid >> 6, lane = tid & 63;
    const int gq = lane >> 4, cl = lane & 15;
    const int x0 = blockIdx.x * 16, y0 = blockIdx.y * 16;
    const int b = blockIdx.z >> 1, br = blockIdx.z & 1;

    const float* in = (br ? g : x) + (size_t)b * NPIX;
    const f16* pA = br ? pA2 : pA1;
    const f16* pBs = br ? pBs2 : pBs1;
    const float bscal = (br ? b2b : b1b)[0];

    for (int t = tid; t < 400; t += 256) {
        int r = t / 20, c = t % 20;
        int gy = y0 - 2 + r, gx = x0 - 2 + c;
        xt[t] = (f16)(((unsigned)gy < (unsigned)HH && (unsigned)gx < (unsigned)WW)
                          ? in[gy * WW + gx] : 0.f);
    }
    if (tid < 64) bA[tid] = (br ? b2a : b1a)[tid];

    // per-lane constant tap offsets for conv1a gather (k>=9 -> weight is 0)
    int koff[8];
    #pragma unroll
    for (int j = 0; j < 8; j++) {
        int k = gq * 8 + j;
        int kc = k < 9 ? k : 0;
        koff[j] = (kc / 3) * 20 + (kc % 3);
    }

    f16x8 afA[4];
    #pragma unroll
    for (int mt = 0; mt < 4; mt++)
        afA[mt] = *(const f16x8*)&pA[(mt * 16 + cl) * 32 + gq * 8];
    f16x8 afS0 = *(const f16x8*)&pBs[cl * 64 + gq * 8];
    f16x8 afS1 = *(const f16x8*)&pBs[cl * 64 + 32 + gq * 8];
    __syncthreads();

    // conv1a: hidden 18x18 region
    for (int nt = wid; nt < 21; nt += 4) {
        int p = nt * 16 + cl;
        int pc = p > 323 ? 323 : p;
        int py = pc / 18, px = pc - 18 * py;
        int base = py * 20 + px;
        f16x8 bf;
        #pragma unroll
        for (int j = 0; j < 8; j++) bf[j] = xt[base + koff[j]];
        int gy = y0 - 1 + py, gx = x0 - 1 + px;
        bool ok = (p < 324) &&
                  ((unsigned)gy < (unsigned)HH && (unsigned)gx < (unsigned)WW);
        #pragma unroll
        for (int mt = 0; mt < 4; mt++) {
            f32x4 z = {0.f, 0.f, 0.f, 0.f};
            f32x4 acc = __builtin_amdgcn_mfma_f32_16x16x32_f16(afA[mt], bf, z, 0, 0, 0);
            if (p < 324) {
                int c0 = mt * 16 + gq * 4;
                union { f16 h[4]; uint2 u2; } pk;
                #pragma unroll
                for (int r = 0; r < 4; r++)
                    pk.h[r] = (f16)(ok ? fmaxf(acc[r] + bA[c0 + r], 0.f) : 0.f);
                *(uint2*)&hid[swzoff(p, c0)] = pk.u2;
            }
        }
    }
    __syncthreads();

    // conv1b partials: part[tap][q] over 18x18 region (2 MFMAs per 16-px tile)
    for (int nt = wid; nt < 21; nt += 4) {
        int p = nt * 16 + cl;
        int pc = p > 323 ? 323 : p;
        f16x8 bf0 = *(const f16x8*)&hid[swzoff(pc, gq * 8)];
        f16x8 bf1 = *(const f16x8*)&hid[swzoff(pc, 32 + gq * 8)];
        f32x4 z = {0.f, 0.f, 0.f, 0.f};
        f32x4 d = __builtin_amdgcn_mfma_f32_16x16x32_f16(afS0, bf0, z, 0, 0, 0);
        d = __builtin_amdgcn_mfma_f32_16x16x32_f16(afS1, bf1, d, 0, 0, 0);
        #pragma unroll
        for (int r = 0; r < 4; r++) {
            int tap = gq * 4 + r;
            if (tap < 9 && p < 324)
                part[tap * 328 + p] = (f16)d[r];
        }
    }
    __syncthreads();

    // final: out[ty][tx] = bias + sum_{u,v} part[u*3+v][(ty+u)*18 + tx+v]
    {
        int ty = tid >> 4, tx = tid & 15;
        float s = bscal;
        #pragma unroll
        for (int u = 0; u < 3; u++)
            #pragma unroll
            for (int v = 0; v < 3; v++)
                s += (float)part[(u * 3 + v) * 328 + (ty + u) * 18 + tx + v];
        feat[((size_t)(b * 2 + br)) * NPIX + (y0 + ty) * WW + x0 + tx] = s;
    }
}

// ---------------------------------------------------------------------------
// K2: feat -> h1 (LDS, 18x18) -> h2 (HBM f16 [ci][pix][64]).
// wfb in two half-passes (acc[2][4]=32 regs) + bounds(256,4): keeps total
// regs <=128 -> 4 waves/SIMD (round-8: acc[4][4]+84 VGPR = 2 waves/SIMD,
// latency-bound at MfmaUtil 10%).
// ---------------------------------------------------------------------------
__global__ __launch_bounds__(256, 4) void k2_wfab(
    const float* __restrict__ feat, const f16* __restrict__ pWa,
    const f16* __restrict__ pWb, const float* __restrict__ bfa,
    const float* __restrict__ bfb, f16* __restrict__ h2g, int b0)
{
    __shared__ f16 ftt[800];      // [2][400] feat tile 20x20
    __shared__ f16 hid[20736];    // h1 [324][64] swz
    __shared__ float bA[64];
    __shared__ float bB[64];

    const int tid = threadIdx.x;
    const int wid = tid >> 6, lane = tid & 63;
    const int gq = lane >> 4, cl = lane & 15;
    const int x0 = blockIdx.x * 16, y0 = blockIdx.y * 16;
    const int ci = blockIdx.z, b = b0 + ci;

    for (int t = tid; t < 800; t += 256) {
        int cin = t / 400, p = t - 400 * cin;
        int r = p / 20, c = p - 20 * r;
        int gy = y0 - 2 + r, gx = x0 - 2 + c;
        ftt[t] = (f16)(((unsigned)gy < (unsigned)HH && (unsigned)gx < (unsigned)WW)
                           ? feat[((size_t)(b * 2 + cin)) * NPIX + gy * WW + gx] : 0.f);
    }
    if (tid < 64) { bA[tid] = bfa[tid]; bB[tid] = bfb[tid]; }

    int koff[8];
    #pragma unroll
    for (int j = 0; j < 8; j++) {
        int k = gq * 8 + j;
        int kc = k < 18 ? k : 0;
        int cin = kc >= 9 ? 1 : 0;
        int tap = kc - 9 * cin;
        koff[j] = cin * 400 + (tap / 3) * 20 + (tap % 3);
    }

    f16x8 afA[4];
    #pragma unroll
    for (int mt = 0; mt < 4; mt++)
        afA[mt] = *(const f16x8*)&pWa[(mt * 16 + cl) * 32 + gq * 8];
    __syncthreads();

    // wfa: h1 18x18, k = cin*9+tap (18, pad 32)
    for (int nt = wid; nt < 21; nt += 4) {
        int p = nt * 16 + cl;
        int pc = p > 323 ? 323 : p;
        int py = pc / 18, px = pc - 18 * py;
        int base = py * 20 + px;
        f16x8 bf;
        #pragma unroll
        for (int j = 0; j < 8; j++) bf[j] = ftt[base + koff[j]];
        int gy = y0 - 1 + py, gx = x0 - 1 + px;
        bool ok = (p < 324) &&
                  ((unsigned)gy < (unsigned)HH && (unsigned)gx < (unsigned)WW);
        #pragma unroll
        for (int mt = 0; mt < 4; mt++) {
            f32x4 z = {0.f, 0.f, 0.f, 0.f};
            f32x4 acc = __builtin_amdgcn_mfma_f32_16x16x32_f16(afA[mt], bf, z, 0, 0, 0);
            if (p < 324) {
                int c0 = mt * 16 + gq * 4;
                union { f16 h[4]; uint2 u2; } pk;
                #pragma unroll
                for (int r = 0; r < 4; r++)
                    pk.h[r] = (f16)(ok ? fmaxf(acc[r] + bA[c0 + r], 0.f) : 0.f);
                *(uint2*)&hid[swzoff(p, c0)] = pk.u2;
            }
        }
    }
    __syncthreads();

    // wfb: h2 16x16 x 64, two half-passes of 2 pixel rows per wave
    #pragma unroll 1
    for (int half = 0; half < 2; half++) {
        f32x4 acc[2][4];
        #pragma unroll
        for (int i = 0; i < 2; i++)
            #pragma unroll
            for (int mt = 0; mt < 4; mt++) acc[i][mt] = (f32x4){0.f, 0.f, 0.f, 0.f};
        #pragma unroll 2
        for (int kk = 0; kk < 18; kk++) {
            int tap = kk >> 1;
            int u = tap / 3, v = tap - 3 * u;
            int c0 = (kk & 1) * 32 + gq * 8;
            f16x8 af[4];
            #pragma unroll
            for (int mt = 0; mt < 4; mt++)
                af[mt] = *(const f16x8*)&pWb[(mt * 16 + cl) * 576 + kk * 32 + gq * 8];
            #pragma unroll
            for (int i = 0; i < 2; i++) {
                int nt = wid * 4 + half * 2 + i;
                int hp = (nt + u) * 18 + cl + v;
                f16x8 bf = *(const f16x8*)&hid[swzoff(hp, c0)];
                #pragma unroll
                for (int mt = 0; mt < 4; mt++)
                    acc[i][mt] = __builtin_amdgcn_mfma_f32_16x16x32_f16(af[mt], bf, acc[i][mt], 0, 0, 0);
            }
        }
        #pragma unroll
        for (int i = 0; i < 2; i++) {
            int nt = wid * 4 + half * 2 + i;        // tile row; pixel col = cl
            size_t pb = ((size_t)ci * NPIX + (size_t)((y0 + nt) * WW + x0 + cl)) * 64;
            #pragma unroll
            for (int mt = 0; mt < 4; mt++) {
                int c0 = mt * 16 + gq * 4;
                union { f16 h[4]; uint2 u2; } pk;
                #pragma unroll
                for (int r = 0; r < 4; r++)
                    pk.h[r] = (f16)fmaxf(acc[i][mt][r] + bB[c0 + r], 0.f);
                *(uint2*)&h2g[pb + c0] = pk.u2;
            }
        }
    }
}

// ---------------------------------------------------------------------------
// K3: h2 -> logits(96) -> softmax(81) -> patch apply -> out.
// Two half-passes (acc[2][6]=48 regs) + bounds(256,4) -> <=128 total regs ->
// 4 waves/SIMD. kk stays at unroll 2 (FULL unroll hoists 108 weight loads ->
// round-5/6 spill disaster; tripwire: k3 WRITE_SIZE must stay ~1 MB).
// ---------------------------------------------------------------------------
__global__ __launch_bounds__(256, 4) void k3_wfc_apply(
    const f16* __restrict__ h2g, const f16* __restrict__ pWc,
    const float* __restrict__ bfc, const float* __restrict__ x,
    float* __restrict__ out, int b0)
{
    __shared__ f16 h2t[20736];    // [324][64] swz
    __shared__ float xt24[576];   // 24x24
    __shared__ float bC[96];

    const int tid = threadIdx.x;
    const int wid = tid >> 6, lane = tid & 63;
    const int gq = lane >> 4, cl = lane & 15;
    const int x0 = blockIdx.x * 16, y0 = blockIdx.y * 16;
    const int ci = blockIdx.z, b = b0 + ci;

    for (int t = tid; t < 2592; t += 256) {
        int p = t >> 3, grp = t & 7;
        int py = p / 18, px = p - 18 * py;
        int gy = y0 - 1 + py, gx = x0 - 1 + px;
        f16x8 v = {};
        if ((unsigned)gy < (unsigned)HH && (unsigned)gx < (unsigned)WW)
            v = *(const f16x8*)&h2g[((size_t)ci * NPIX + (size_t)(gy * WW + gx)) * 64 + grp * 8];
        *(f16x8*)&h2t[swzoff(p, grp * 8)] = v;
    }
    const float* xb = x + (size_t)b * NPIX;
    for (int t = tid; t < 576; t += 256) {
        int r = t / 24, c = t - 24 * r;
        int gy = y0 - 4 + r, gx = x0 - 4 + c;
        xt24[t] = ((unsigned)gy < (unsigned)HH && (unsigned)gx < (unsigned)WW)
                      ? xb[gy * WW + gx] : 0.f;
    }
    if (tid < 96) bC[tid] = tid < 81 ? bfc[tid] : 0.f;
    __syncthreads();

    #pragma unroll 1
    for (int half = 0; half < 2; half++) {
        f32x4 acc[2][6];
        #pragma unroll
        for (int i = 0; i < 2; i++)
            #pragma unroll
            for (int mt = 0; mt < 6; mt++) acc[i][mt] = (f32x4){0.f, 0.f, 0.f, 0.f};

        #pragma unroll 2
        for (int kk = 0; kk < 18; kk++) {
            int tap = kk >> 1;
            int u = tap / 3, v = tap - 3 * u;
            int c0 = (kk & 1) * 32 + gq * 8;
            f16x8 af[6];
            #pragma unroll
            for (int mt = 0; mt < 6; mt++)
                af[mt] = *(const f16x8*)&pWc[(mt * 16 + cl) * 576 + kk * 32 + gq * 8];
            #pragma unroll
            for (int i = 0; i < 2; i++) {
                int nt = wid * 4 + half * 2 + i;
                int hp = (nt + u) * 18 + cl + v;
                f16x8 bf = *(const f16x8*)&h2t[swzoff(hp, c0)];
                #pragma unroll
                for (int mt = 0; mt < 6; mt++)
                    acc[i][mt] = __builtin_amdgcn_mfma_f32_16x16x32_f16(af[mt], bf, acc[i][mt], 0, 0, 0);
            }
        }

        // softmax over taps for each pixel (col=cl); reduce across gq lanes
        #pragma unroll
        for (int i = 0; i < 2; i++) {
            int nt = wid * 4 + half * 2 + i;        // pixel row; pixel col = cl
            float val[6][4];
            float m = -1e30f;
            #pragma unroll
            for (int mt = 0; mt < 6; mt++)
                #pragma unroll
                for (int r = 0; r < 4; r++) {
                    int c = mt * 16 + gq * 4 + r;
                    float vv = (c <= 80) ? acc[i][mt][r] + bC[c] : -1e30f;
                    val[mt][r] = vv;
                    m = fmaxf(m, vv);
                }
            m = fmaxf(m, __shfl_xor(m, 16));
            m = fmaxf(m, __shfl_xor(m, 32));
            float s = 0.f, o = 0.f;
            #pragma unroll
            for (int mt = 0; mt < 6; mt++)
                #pragma unroll
                for (int r = 0; r < 4; r++) {
                    int c = mt * 16 + gq * 4 + r;
                    if (c <= 80) {
                        float e = __expf(val[mt][r] - m);
                        int u9 = c / 9, v9 = c - 9 * u9;
                        s += e;
                        o += e * xt24[(nt + u9) * 24 + cl + v9];
                    }
                }
            s += __shfl_xor(s, 16); s += __shfl_xor(s, 32);
            o += __shfl_xor(o, 16); o += __shfl_xor(o, 32);
            if (gq == 0)
                out[(size_t)b * NPIX + (y0 + nt) * WW + x0 + cl] = o / s;
        }
    }
}

// ---------------------------------------------------------------------------
extern "C" void kernel_launch(void* const* d_in, const int* in_sizes, int n_in,
                              void* d_out, int out_size, void* d_ws, size_t ws_size,
                              hipStream_t stream)
{
    const float* x   = (const float*)d_in[0];
    const float* g   = (const float*)d_in[1];
    const float* w1a = (const float*)d_in[2];  const float* b1a = (const float*)d_in[3];
    const float* w1b = (const float*)d_in[4];  const float* b1b = (const float*)d_in[5];
    const float* w2a = (const float*)d_in[6];  const float* b2a = (const float*)d_in[7];
    const float* w2b = (const float*)d_in[8];  const float* b2b = (const float*)d_in[9];
    const float* wfa = (const float*)d_in[10]; const float* bfa = (const float*)d_in[11];
    const float* wfb = (const float*)d_in[12]; const float* bfb = (const float*)d_in[13];
    const float* wfc = (const float*)d_in[14]; const float* bfc = (const float*)d_in[15];
    float* out = (float*)d_out;

    // workspace: feat f32 | h2 chunk f16 | packed weights f16
    float* feat = (float*)d_ws;                       // 2,097,152 f32
    size_t featB = 2097152ull * 4;
    size_t pkB = 100352ull * 2;
    int nbc = 4;
    while (nbc > 1 && featB + (size_t)nbc * NPIX * 64 * 2 + pkB > ws_size) nbc >>= 1;

    f16* h2g = (f16*)((char*)d_ws + featB);
    f16* pk  = h2g + (size_t)nbc * NPIX * 64;
    f16* pA1  = pk;             // 2048
    f16* pA2  = pA1 + 2048;     // 2048
    f16* pWa  = pA2 + 2048;     // 2048
    f16* pBs1 = pWa + 2048;     // 1024
    f16* pBs2 = pBs1 + 1024;    // 1024
    f16* pWb  = pBs2 + 1024;    // 36864
    f16* pWc  = pWb + 36864;    // 55296

    prepack_kernel<<<dim3(216), 256, 0, stream>>>(
        w1a, w2a, w1b, w2b, wfa, wfb, wfc, pA1, pA2, pWa, pBs1, pBs2, pWb, pWc);

    k1_branch<<<dim3(16, 16, 32), 256, 0, stream>>>(
        x, g, b1a, b2a, b1b, b2b, pA1, pA2, pBs1, pBs2, feat);

    for (int b0 = 0; b0 < NB; b0 += nbc) {
        int cn = (NB - b0) < nbc ? (NB - b0) : nbc;
        k2_wfab<<<dim3(16, 16, cn), 256, 0, stream>>>(
            feat, pWa, pWb, bfa, bfb, h2g, b0);
        k3_wfc_apply<<<dim3(16, 16, cn), 256, 0, stream>>>(
            h2g, pWc, bfc, x, out, b0);
    }
}

// Round 10
// 440.499 us; speedup vs baseline: 1.9949x; 1.9949x over previous
//
#include <hip/hip_runtime.h>

#define NB 16
#define HH 256
#define WW 256
#define NPIX (HH*WW)

typedef _Float16 f16;
typedef _Float16 f16x8 __attribute__((ext_vector_type(8)));
typedef float f32x4 __attribute__((ext_vector_type(4)));

// slotted+swizzled f16 LDS tile [P][64]: slot (16B, 8 f16) index XOR'd with p&7
__device__ __forceinline__ int swzoff(int p, int c) {
    return p * 64 + ((((c >> 3) ^ (p & 7)) << 3) | (c & 7));
}

// ---------------------------------------------------------------------------
// prepack: all weights -> f16 packed.
// pA1/pA2 [64][32] k=tap(9,pad32); pWa [64][32] k=cin*9+tap(18,pad32);
// pBs1/pBs2 [16][64] tap-shifted conv1b: row=tap(9 used), col=cin;
// pWb [64][576] k=tap*64+cin; pWc [96][576] rows81-95 zero.
// ---------------------------------------------------------------------------
__global__ __launch_bounds__(256) void prepack_kernel(
    const float* __restrict__ w1a, const float* __restrict__ w2a,
    const float* __restrict__ w1b, const float* __restrict__ w2b,
    const float* __restrict__ wfa, const float* __restrict__ wfb,
    const float* __restrict__ wfc,
    f16* __restrict__ pA1, f16* __restrict__ pA2, f16* __restrict__ pWa,
    f16* __restrict__ pBs1, f16* __restrict__ pBs2,
    f16* __restrict__ pWb, f16* __restrict__ pWc)
{
    int i = blockIdx.x * 256 + threadIdx.x;
    if (i < 2048) {
        int c = i >> 5, k = i & 31;
        pA1[i] = (f16)(k < 9 ? w1a[c * 9 + k] : 0.f);
        pA2[i] = (f16)(k < 9 ? w2a[c * 9 + k] : 0.f);
        pWa[i] = (f16)(k < 18 ? wfa[c * 18 + k] : 0.f);
    }
    if (i < 1024) {
        int r = i >> 6, cin = i & 63;   // row = tap, col = cin
        pBs1[i] = (f16)(r < 9 ? w1b[cin * 9 + r] : 0.f);
        pBs2[i] = (f16)(r < 9 ? w2b[cin * 9 + r] : 0.f);
    }
    if (i < 36864) {
        int c = i / 576, k = i % 576;
        int tap = k >> 6, cin = k & 63;
        pWb[i] = (f16)wfb[(c * 64 + cin) * 9 + tap];
    }
    if (i < 55296) {
        int r = i / 576, k = i % 576;
        int tap = k >> 6, cin = k & 63;
        pWc[i] = (f16)(r < 81 ? wfc[(r * 64 + cin) * 9 + tap] : 0.f);
    }
}

// ---------------------------------------------------------------------------
// K1: branch -> feat.  blockIdx.z = b*2+br.
// conv1a via MFMA (K=9 pad 32) -> hid 18x18x64 in LDS (swz).
// conv1b via TAP-SHIFTED MFMA: part[tap][q] = sum_cin w[cin][tap]*hid[q][cin],
// then out = 9-term LDS sum.  (unchanged from round 8)
// ---------------------------------------------------------------------------
__global__ __launch_bounds__(256, 3) void k1_branch(
    const float* __restrict__ x, const float* __restrict__ g,
    const float* __restrict__ b1a, const float* __restrict__ b2a,
    const float* __restrict__ b1b, const float* __restrict__ b2b,
    const f16* __restrict__ pA1, const f16* __restrict__ pA2,
    const f16* __restrict__ pBs1, const f16* __restrict__ pBs2,
    float* __restrict__ feat)
{
    __shared__ f16 xt[400];       // 20x20 input tile
    __shared__ f16 hid[20736];    // [324][64] swz
    __shared__ f16 part[9 * 328]; // conv1b tap partials over 18x18 region
    __shared__ float bA[64];

    const int tid = threadIdx.x;
    const int wid = tid >> 6, lane = tid & 63;
    const int gq = lane >> 4, cl = lane & 15;
    const int x0 = blockIdx.x * 16, y0 = blockIdx.y * 16;
    const int b = blockIdx.z >> 1, br = blockIdx.z & 1;

    const float* in = (br ? g : x) + (size_t)b * NPIX;
    const f16* pA = br ? pA2 : pA1;
    const f16* pBs = br ? pBs2 : pBs1;
    const float bscal = (br ? b2b : b1b)[0];

    for (int t = tid; t < 400; t += 256) {
        int r = t / 20, c = t % 20;
        int gy = y0 - 2 + r, gx = x0 - 2 + c;
        xt[t] = (f16)(((unsigned)gy < (unsigned)HH && (unsigned)gx < (unsigned)WW)
                          ? in[gy * WW + gx] : 0.f);
    }
    if (tid < 64) bA[tid] = (br ? b2a : b1a)[tid];

    int koff[8];
    #pragma unroll
    for (int j = 0; j < 8; j++) {
        int k = gq * 8 + j;
        int kc = k < 9 ? k : 0;
        koff[j] = (kc / 3) * 20 + (kc % 3);
    }

    f16x8 afA[4];
    #pragma unroll
    for (int mt = 0; mt < 4; mt++)
        afA[mt] = *(const f16x8*)&pA[(mt * 16 + cl) * 32 + gq * 8];
    f16x8 afS0 = *(const f16x8*)&pBs[cl * 64 + gq * 8];
    f16x8 afS1 = *(const f16x8*)&pBs[cl * 64 + 32 + gq * 8];
    __syncthreads();

    // conv1a: hidden 18x18 region
    for (int nt = wid; nt < 21; nt += 4) {
        int p = nt * 16 + cl;
        int pc = p > 323 ? 323 : p;
        int py = pc / 18, px = pc - 18 * py;
        int base = py * 20 + px;
        f16x8 bf;
        #pragma unroll
        for (int j = 0; j < 8; j++) bf[j] = xt[base + koff[j]];
        int gy = y0 - 1 + py, gx = x0 - 1 + px;
        bool ok = (p < 324) &&
                  ((unsigned)gy < (unsigned)HH && (unsigned)gx < (unsigned)WW);
        #pragma unroll
        for (int mt = 0; mt < 4; mt++) {
            f32x4 z = {0.f, 0.f, 0.f, 0.f};
            f32x4 acc = __builtin_amdgcn_mfma_f32_16x16x32_f16(afA[mt], bf, z, 0, 0, 0);
            if (p < 324) {
                int c0 = mt * 16 + gq * 4;
                union { f16 h[4]; uint2 u2; } pk;
                #pragma unroll
                for (int r = 0; r < 4; r++)
                    pk.h[r] = (f16)(ok ? fmaxf(acc[r] + bA[c0 + r], 0.f) : 0.f);
                *(uint2*)&hid[swzoff(p, c0)] = pk.u2;
            }
        }
    }
    __syncthreads();

    // conv1b partials
    for (int nt = wid; nt < 21; nt += 4) {
        int p = nt * 16 + cl;
        int pc = p > 323 ? 323 : p;
        f16x8 bf0 = *(const f16x8*)&hid[swzoff(pc, gq * 8)];
        f16x8 bf1 = *(const f16x8*)&hid[swzoff(pc, 32 + gq * 8)];
        f32x4 z = {0.f, 0.f, 0.f, 0.f};
        f32x4 d = __builtin_amdgcn_mfma_f32_16x16x32_f16(afS0, bf0, z, 0, 0, 0);
        d = __builtin_amdgcn_mfma_f32_16x16x32_f16(afS1, bf1, d, 0, 0, 0);
        #pragma unroll
        for (int r = 0; r < 4; r++) {
            int tap = gq * 4 + r;
            if (tap < 9 && p < 324)
                part[tap * 328 + p] = (f16)d[r];
        }
    }
    __syncthreads();

    {
        int ty = tid >> 4, tx = tid & 15;
        float s = bscal;
        #pragma unroll
        for (int u = 0; u < 3; u++)
            #pragma unroll
            for (int v = 0; v < 3; v++)
                s += (float)part[(u * 3 + v) * 328 + (ty + u) * 18 + tx + v];
        feat[((size_t)(b * 2 + br)) * NPIX + (y0 + ty) * WW + x0 + tx] = s;
    }
}

// ---------------------------------------------------------------------------
// K2: feat -> h1 (LDS, 18x18) -> h2 (HBM f16 [ci][pix][64]).
// wfb weights staged per-kk into LDS (wbufB [64][36], pad-36 -> 16 distinct
// banks across cl): replaces 72 per-wave L2 loads with 1 cooperative load
// per kk (4x traffic cut) + conflict-free ds_read_b128.
// ---------------------------------------------------------------------------
__global__ __launch_bounds__(256, 3) void k2_wfab(
    const float* __restrict__ feat, const f16* __restrict__ pWa,
    const f16* __restrict__ pWb, const float* __restrict__ bfa,
    const float* __restrict__ bfb, f16* __restrict__ h2g, int b0)
{
    __shared__ f16 ftt[800];      // [2][400] feat tile 20x20
    __shared__ f16 hid[20736];    // h1 [324][64] swz
    __shared__ f16 wbufB[64 * 36];// per-kk weight chunk, pad 36
    __shared__ float bA[64];
    __shared__ float bB[64];

    const int tid = threadIdx.x;
    const int wid = tid >> 6, lane = tid & 63;
    const int gq = lane >> 4, cl = lane & 15;
    const int x0 = blockIdx.x * 16, y0 = blockIdx.y * 16;
    const int ci = blockIdx.z, b = b0 + ci;

    for (int t = tid; t < 800; t += 256) {
        int cin = t / 400, p = t - 400 * cin;
        int r = p / 20, c = p - 20 * r;
        int gy = y0 - 2 + r, gx = x0 - 2 + c;
        ftt[t] = (f16)(((unsigned)gy < (unsigned)HH && (unsigned)gx < (unsigned)WW)
                           ? feat[((size_t)(b * 2 + cin)) * NPIX + gy * WW + gx] : 0.f);
    }
    if (tid < 64) { bA[tid] = bfa[tid]; bB[tid] = bfb[tid]; }

    int koff[8];
    #pragma unroll
    for (int j = 0; j < 8; j++) {
        int k = gq * 8 + j;
        int kc = k < 18 ? k : 0;
        int cin = kc >= 9 ? 1 : 0;
        int tap = kc - 9 * cin;
        koff[j] = cin * 400 + (tap / 3) * 20 + (tap % 3);
    }

    f16x8 afA[4];
    #pragma unroll
    for (int mt = 0; mt < 4; mt++)
        afA[mt] = *(const f16x8*)&pWa[(mt * 16 + cl) * 32 + gq * 8];
    __syncthreads();

    // wfa: h1 18x18, k = cin*9+tap (18, pad 32)
    for (int nt = wid; nt < 21; nt += 4) {
        int p = nt * 16 + cl;
        int pc = p > 323 ? 323 : p;
        int py = pc / 18, px = pc - 18 * py;
        int base = py * 20 + px;
        f16x8 bf;
        #pragma unroll
        for (int j = 0; j < 8; j++) bf[j] = ftt[base + koff[j]];
        int gy = y0 - 1 + py, gx = x0 - 1 + px;
        bool ok = (p < 324) &&
                  ((unsigned)gy < (unsigned)HH && (unsigned)gx < (unsigned)WW);
        #pragma unroll
        for (int mt = 0; mt < 4; mt++) {
            f32x4 z = {0.f, 0.f, 0.f, 0.f};
            f32x4 acc = __builtin_amdgcn_mfma_f32_16x16x32_f16(afA[mt], bf, z, 0, 0, 0);
            if (p < 324) {
                int c0 = mt * 16 + gq * 4;
                union { f16 h[4]; uint2 u2; } pk;
                #pragma unroll
                for (int r = 0; r < 4; r++)
                    pk.h[r] = (f16)(ok ? fmaxf(acc[r] + bA[c0 + r], 0.f) : 0.f);
                *(uint2*)&hid[swzoff(p, c0)] = pk.u2;
            }
        }
    }
    __syncthreads();

    // wfb: h2 16x16 x 64, LDS-staged weights, single acc pass (round-8 acc)
    f32x4 acc[4][4];
    #pragma unroll
    for (int i = 0; i < 4; i++)
        #pragma unroll
        for (int mt = 0; mt < 4; mt++) acc[i][mt] = (f32x4){0.f, 0.f, 0.f, 0.f};
    #pragma unroll 1
    for (int kk = 0; kk < 18; kk++) {
        // stage this kk's [64][32] chunk: exactly 1 f16x8 per thread
        *(f16x8*)&wbufB[(tid >> 2) * 36 + (tid & 3) * 8] =
            *(const f16x8*)&pWb[(tid >> 2) * 576 + kk * 32 + (tid & 3) * 8];
        __syncthreads();
        int tap = kk >> 1;
        int u = tap / 3, v = tap - 3 * u;
        int c0 = (kk & 1) * 32 + gq * 8;
        f16x8 af[4];
        #pragma unroll
        for (int mt = 0; mt < 4; mt++)
            af[mt] = *(const f16x8*)&wbufB[(mt * 16 + cl) * 36 + gq * 8];
        #pragma unroll
        for (int i = 0; i < 4; i++) {
            int nt = wid * 4 + i;
            int hp = (nt + u) * 18 + cl + v;
            f16x8 bf = *(const f16x8*)&hid[swzoff(hp, c0)];
            #pragma unroll
            for (int mt = 0; mt < 4; mt++)
                acc[i][mt] = __builtin_amdgcn_mfma_f32_16x16x32_f16(af[mt], bf, acc[i][mt], 0, 0, 0);
        }
        __syncthreads();
    }
    #pragma unroll
    for (int i = 0; i < 4; i++) {
        int nt = wid * 4 + i;                       // tile row; pixel col = cl
        size_t pb = ((size_t)ci * NPIX + (size_t)((y0 + nt) * WW + x0 + cl)) * 64;
        #pragma unroll
        for (int mt = 0; mt < 4; mt++) {
            int c0 = mt * 16 + gq * 4;
            union { f16 h[4]; uint2 u2; } pk;
            #pragma unroll
            for (int r = 0; r < 4; r++)
                pk.h[r] = (f16)fmaxf(acc[i][mt][r] + bB[c0 + r], 0.f);
            *(uint2*)&h2g[pb + c0] = pk.u2;
        }
    }
}

// ---------------------------------------------------------------------------
// K3: h2 -> logits(96) -> softmax(81) -> patch apply -> out.
// Round-8 structure (single pass, acc[4][6]) + per-kk LDS weight staging
// (wbufC [96][36]): 108 per-wave L2 loads -> 1.5 cooperative loads/thread/kk.
// kk loop stays unroll 1 so staging loads can't be hoisted (round-5/6 spill;
// tripwire: WRITE_SIZE must stay ~1 MB).
// ---------------------------------------------------------------------------
__global__ __launch_bounds__(256, 3) void k3_wfc_apply(
    const f16* __restrict__ h2g, const f16* __restrict__ pWc,
    const float* __restrict__ bfc, const float* __restrict__ x,
    float* __restrict__ out, int b0)
{
    __shared__ f16 h2t[20736];    // [324][64] swz
    __shared__ f16 wbufC[96 * 36];// per-kk weight chunk, pad 36
    __shared__ float xt24[576];   // 24x24
    __shared__ float bC[96];

    const int tid = threadIdx.x;
    const int wid = tid >> 6, lane = tid & 63;
    const int gq = lane >> 4, cl = lane & 15;
    const int x0 = blockIdx.x * 16, y0 = blockIdx.y * 16;
    const int ci = blockIdx.z, b = b0 + ci;

    for (int t = tid; t < 2592; t += 256) {
        int p = t >> 3, grp = t & 7;
        int py = p / 18, px = p - 18 * py;
        int gy = y0 - 1 + py, gx = x0 - 1 + px;
        f16x8 v = {};
        if ((unsigned)gy < (unsigned)HH && (unsigned)gx < (unsigned)WW)
            v = *(const f16x8*)&h2g[((size_t)ci * NPIX + (size_t)(gy * WW + gx)) * 64 + grp * 8];
        *(f16x8*)&h2t[swzoff(p, grp * 8)] = v;
    }
    const float* xb = x + (size_t)b * NPIX;
    for (int t = tid; t < 576; t += 256) {
        int r = t / 24, c = t - 24 * r;
        int gy = y0 - 4 + r, gx = x0 - 4 + c;
        xt24[t] = ((unsigned)gy < (unsigned)HH && (unsigned)gx < (unsigned)WW)
                      ? xb[gy * WW + gx] : 0.f;
    }
    if (tid < 96) bC[tid] = tid < 81 ? bfc[tid] : 0.f;
    __syncthreads();

    f32x4 acc[4][6];
    #pragma unroll
    for (int i = 0; i < 4; i++)
        #pragma unroll
        for (int mt = 0; mt < 6; mt++) acc[i][mt] = (f32x4){0.f, 0.f, 0.f, 0.f};
    #pragma unroll 1
    for (int kk = 0; kk < 18; kk++) {
        // stage this kk's [96][32] chunk: 384 f16x8 items over 256 threads
        for (int t = tid; t < 384; t += 256)
            *(f16x8*)&wbufC[(t >> 2) * 36 + (t & 3) * 8] =
                *(const f16x8*)&pWc[(t >> 2) * 576 + kk * 32 + (t & 3) * 8];
        __syncthreads();
        int tap = kk >> 1;
        int u = tap / 3, v = tap - 3 * u;
        int c0 = (kk & 1) * 32 + gq * 8;
        f16x8 af[6];
        #pragma unroll
        for (int mt = 0; mt < 6; mt++)
            af[mt] = *(const f16x8*)&wbufC[(mt * 16 + cl) * 36 + gq * 8];
        #pragma unroll
        for (int i = 0; i < 4; i++) {
            int nt = wid * 4 + i;
            int hp = (nt + u) * 18 + cl + v;
            f16x8 bf = *(const f16x8*)&h2t[swzoff(hp, c0)];
            #pragma unroll
            for (int mt = 0; mt < 6; mt++)
                acc[i][mt] = __builtin_amdgcn_mfma_f32_16x16x32_f16(af[mt], bf, acc[i][mt], 0, 0, 0);
        }
        __syncthreads();
    }

    // softmax over taps (rows) for each pixel (col=cl); reduce across gq lanes
    #pragma unroll
    for (int i = 0; i < 4; i++) {
        int nt = wid * 4 + i;                       // pixel row; pixel col = cl
        float val[6][4];
        float m = -1e30f;
        #pragma unroll
        for (int mt = 0; mt < 6; mt++)
            #pragma unroll
            for (int r = 0; r < 4; r++) {
                int c = mt * 16 + gq * 4 + r;
                float vv = (c <= 80) ? acc[i][mt][r] + bC[c] : -1e30f;
                val[mt][r] = vv;
                m = fmaxf(m, vv);
            }
        m = fmaxf(m, __shfl_xor(m, 16));
        m = fmaxf(m, __shfl_xor(m, 32));
        float s = 0.f, o = 0.f;
        #pragma unroll
        for (int mt = 0; mt < 6; mt++)
            #pragma unroll
            for (int r = 0; r < 4; r++) {
                int c = mt * 16 + gq * 4 + r;
                if (c <= 80) {
                    float e = __expf(val[mt][r] - m);
                    int u9 = c / 9, v9 = c - 9 * u9;
                    s += e;
                    o += e * xt24[(nt + u9) * 24 + cl + v9];
                }
            }
        s += __shfl_xor(s, 16); s += __shfl_xor(s, 32);
        o += __shfl_xor(o, 16); o += __shfl_xor(o, 32);
        if (gq == 0)
            out[(size_t)b * NPIX + (y0 + nt) * WW + x0 + cl] = o / s;
    }
}

// ---------------------------------------------------------------------------
extern "C" void kernel_launch(void* const* d_in, const int* in_sizes, int n_in,
                              void* d_out, int out_size, void* d_ws, size_t ws_size,
                              hipStream_t stream)
{
    const float* x   = (const float*)d_in[0];
    const float* g   = (const float*)d_in[1];
    const float* w1a = (const float*)d_in[2];  const float* b1a = (const float*)d_in[3];
    const float* w1b = (const float*)d_in[4];  const float* b1b = (const float*)d_in[5];
    const float* w2a = (const float*)d_in[6];  const float* b2a = (const float*)d_in[7];
    const float* w2b = (const float*)d_in[8];  const float* b2b = (const float*)d_in[9];
    const float* wfa = (const float*)d_in[10]; const float* bfa = (const float*)d_in[11];
    const float* wfb = (const float*)d_in[12]; const float* bfb = (const float*)d_in[13];
    const float* wfc = (const float*)d_in[14]; const float* bfc = (const float*)d_in[15];
    float* out = (float*)d_out;

    // workspace: feat f32 | h2 chunk f16 | packed weights f16
    float* feat = (float*)d_ws;                       // 2,097,152 f32
    size_t featB = 2097152ull * 4;
    size_t pkB = 100352ull * 2;
    int nbc = 4;
    while (nbc > 1 && featB + (size_t)nbc * NPIX * 64 * 2 + pkB > ws_size) nbc >>= 1;

    f16* h2g = (f16*)((char*)d_ws + featB);
    f16* pk  = h2g + (size_t)nbc * NPIX * 64;
    f16* pA1  = pk;             // 2048
    f16* pA2  = pA1 + 2048;     // 2048
    f16* pWa  = pA2 + 2048;     // 2048
    f16* pBs1 = pWa + 2048;     // 1024
    f16* pBs2 = pBs1 + 1024;    // 1024
    f16* pWb  = pBs2 + 1024;    // 36864
    f16* pWc  = pWb + 36864;    // 55296

    prepack_kernel<<<dim3(216), 256, 0, stream>>>(
        w1a, w2a, w1b, w2b, wfa, wfb, wfc, pA1, pA2, pWa, pBs1, pBs2, pWb, pWc);

    k1_branch<<<dim3(16, 16, 32), 256, 0, stream>>>(
        x, g, b1a, b2a, b1b, b2b, pA1, pA2, pBs1, pBs2, feat);

    for (int b0 = 0; b0 < NB; b0 += nbc) {
        int cn = (NB - b0) < nbc ? (NB - b0) : nbc;
        k2_wfab<<<dim3(16, 16, cn), 256, 0, stream>>>(
            feat, pWa, pWb, bfa, bfb, h2g, b0);
        k3_wfc_apply<<<dim3(16, 16, cn), 256, 0, stream>>>(
            h2g, pWc, bfc, x, out, b0);
    }
}

// Round 11
// 331.088 us; speedup vs baseline: 2.6542x; 1.3305x over previous
//
#include <hip/hip_runtime.h>

#define NB 16
#define HH 256
#define WW 256
#define NPIX (HH*WW)

typedef _Float16 f16;
typedef _Float16 f16x8 __attribute__((ext_vector_type(8)));
typedef float f32x4 __attribute__((ext_vector_type(4)));

// slotted+swizzled f16 LDS tile [P][64]: slot (16B, 8 f16) index XOR'd with p&7
__device__ __forceinline__ int swzoff(int p, int c) {
    return p * 64 + ((((c >> 3) ^ (p & 7)) << 3) | (c & 7));
}

// ---------------------------------------------------------------------------
// prepack: all weights -> f16 packed.
// pA1/pA2 [64][32] k=tap(9,pad32); pWa [64][32] k=cin*9+tap(18,pad32);
// pBs1/pBs2 [16][64] tap-shifted conv1b: row=tap(9 used), col=cin;
// pWb [64][576] k=tap*64+cin; pWc [96][576] rows81-95 zero.
// ---------------------------------------------------------------------------
__global__ __launch_bounds__(256) void prepack_kernel(
    const float* __restrict__ w1a, const float* __restrict__ w2a,
    const float* __restrict__ w1b, const float* __restrict__ w2b,
    const float* __restrict__ wfa, const float* __restrict__ wfb,
    const float* __restrict__ wfc,
    f16* __restrict__ pA1, f16* __restrict__ pA2, f16* __restrict__ pWa,
    f16* __restrict__ pBs1, f16* __restrict__ pBs2,
    f16* __restrict__ pWb, f16* __restrict__ pWc)
{
    int i = blockIdx.x * 256 + threadIdx.x;
    if (i < 2048) {
        int c = i >> 5, k = i & 31;
        pA1[i] = (f16)(k < 9 ? w1a[c * 9 + k] : 0.f);
        pA2[i] = (f16)(k < 9 ? w2a[c * 9 + k] : 0.f);
        pWa[i] = (f16)(k < 18 ? wfa[c * 18 + k] : 0.f);
    }
    if (i < 1024) {
        int r = i >> 6, cin = i & 63;   // row = tap, col = cin
        pBs1[i] = (f16)(r < 9 ? w1b[cin * 9 + r] : 0.f);
        pBs2[i] = (f16)(r < 9 ? w2b[cin * 9 + r] : 0.f);
    }
    if (i < 36864) {
        int c = i / 576, k = i % 576;
        int tap = k >> 6, cin = k & 63;
        pWb[i] = (f16)wfb[(c * 64 + cin) * 9 + tap];
    }
    if (i < 55296) {
        int r = i / 576, k = i % 576;
        int tap = k >> 6, cin = k & 63;
        pWc[i] = (f16)(r < 81 ? wfc[(r * 64 + cin) * 9 + tap] : 0.f);
    }
}

// ---------------------------------------------------------------------------
// K1: branch -> feat.  blockIdx.z = b*2+br.
// conv1a via MFMA (K=9 pad 32) -> hid 18x18x64 in LDS (swz).
// conv1b via TAP-SHIFTED MFMA, then out = 9-term LDS sum.
// Gather loops static-unrolled (6 iters) so the 8-deep ds_read_u16 chains
// software-pipeline across iterations (round-10: latency-bound, not pipe).
// ---------------------------------------------------------------------------
__global__ __launch_bounds__(256, 3) void k1_branch(
    const float* __restrict__ x, const float* __restrict__ g,
    const float* __restrict__ b1a, const float* __restrict__ b2a,
    const float* __restrict__ b1b, const float* __restrict__ b2b,
    const f16* __restrict__ pA1, const f16* __restrict__ pA2,
    const f16* __restrict__ pBs1, const f16* __restrict__ pBs2,
    float* __restrict__ feat)
{
    __shared__ f16 xt[400];       // 20x20 input tile
    __shared__ f16 hid[20736];    // [324][64] swz
    __shared__ f16 part[9 * 328]; // conv1b tap partials over 18x18 region
    __shared__ float bA[64];

    const int tid = threadIdx.x;
    const int wid = tid >> 6, lane = tid & 63;
    const int gq = lane >> 4, cl = lane & 15;
    const int x0 = blockIdx.x * 16, y0 = blockIdx.y * 16;
    const int b = blockIdx.z >> 1, br = blockIdx.z & 1;

    const float* in = (br ? g : x) + (size_t)b * NPIX;
    const f16* pA = br ? pA2 : pA1;
    const f16* pBs = br ? pBs2 : pBs1;
    const float bscal = (br ? b2b : b1b)[0];

    for (int t = tid; t < 400; t += 256) {
        int r = t / 20, c = t % 20;
        int gy = y0 - 2 + r, gx = x0 - 2 + c;
        xt[t] = (f16)(((unsigned)gy < (unsigned)HH && (unsigned)gx < (unsigned)WW)
                          ? in[gy * WW + gx] : 0.f);
    }
    if (tid < 64) bA[tid] = (br ? b2a : b1a)[tid];

    int koff[8];
    #pragma unroll
    for (int j = 0; j < 8; j++) {
        int k = gq * 8 + j;
        int kc = k < 9 ? k : 0;
        koff[j] = (kc / 3) * 20 + (kc % 3);
    }

    f16x8 afA[4];
    #pragma unroll
    for (int mt = 0; mt < 4; mt++)
        afA[mt] = *(const f16x8*)&pA[(mt * 16 + cl) * 32 + gq * 8];
    f16x8 afS0 = *(const f16x8*)&pBs[cl * 64 + gq * 8];
    f16x8 afS1 = *(const f16x8*)&pBs[cl * 64 + 32 + gq * 8];
    __syncthreads();

    // conv1a: hidden 18x18 region (static 6-iter unroll)
    #pragma unroll
    for (int it = 0; it < 6; it++) {
        int nt = wid + it * 4;
        if (nt < 21) {
            int p = nt * 16 + cl;
            int pc = p > 323 ? 323 : p;
            int py = pc / 18, px = pc - 18 * py;
            int base = py * 20 + px;
            f16x8 bf;
            #pragma unroll
            for (int j = 0; j < 8; j++) bf[j] = xt[base + koff[j]];
            int gy = y0 - 1 + py, gx = x0 - 1 + px;
            bool ok = (p < 324) &&
                      ((unsigned)gy < (unsigned)HH && (unsigned)gx < (unsigned)WW);
            #pragma unroll
            for (int mt = 0; mt < 4; mt++) {
                f32x4 z = {0.f, 0.f, 0.f, 0.f};
                f32x4 acc = __builtin_amdgcn_mfma_f32_16x16x32_f16(afA[mt], bf, z, 0, 0, 0);
                if (p < 324) {
                    int c0 = mt * 16 + gq * 4;
                    union { f16 h[4]; uint2 u2; } pk;
                    #pragma unroll
                    for (int r = 0; r < 4; r++)
                        pk.h[r] = (f16)(ok ? fmaxf(acc[r] + bA[c0 + r], 0.f) : 0.f);
                    *(uint2*)&hid[swzoff(p, c0)] = pk.u2;
                }
            }
        }
    }
    __syncthreads();

    // conv1b partials (static 6-iter unroll)
    #pragma unroll
    for (int it = 0; it < 6; it++) {
        int nt = wid + it * 4;
        if (nt < 21) {
            int p = nt * 16 + cl;
            int pc = p > 323 ? 323 : p;
            f16x8 bf0 = *(const f16x8*)&hid[swzoff(pc, gq * 8)];
            f16x8 bf1 = *(const f16x8*)&hid[swzoff(pc, 32 + gq * 8)];
            f32x4 z = {0.f, 0.f, 0.f, 0.f};
            f32x4 d = __builtin_amdgcn_mfma_f32_16x16x32_f16(afS0, bf0, z, 0, 0, 0);
            d = __builtin_amdgcn_mfma_f32_16x16x32_f16(afS1, bf1, d, 0, 0, 0);
            #pragma unroll
            for (int r = 0; r < 4; r++) {
                int tap = gq * 4 + r;
                if (tap < 9 && p < 324)
                    part[tap * 328 + p] = (f16)d[r];
            }
        }
    }
    __syncthreads();

    {
        int ty = tid >> 4, tx = tid & 15;
        float s = bscal;
        #pragma unroll
        for (int u = 0; u < 3; u++)
            #pragma unroll
            for (int v = 0; v < 3; v++)
                s += (float)part[(u * 3 + v) * 328 + (ty + u) * 18 + tx + v];
        feat[((size_t)(b * 2 + br)) * NPIX + (y0 + ty) * WW + x0 + tx] = s;
    }
}

// ---------------------------------------------------------------------------
// K2: feat -> h1 (LDS, 18x18) -> h2 (HBM f16 [ci][pix][64]).
// wfb: 2-kk phases (pair (2t,2t+1) = one tap, 64 contiguous k-cols) staged
// into wbufB [64][72] -> barriers 36->18; T14 async split (next chunk loaded
// to regs before the MFMA burst, ds_write after the barrier).
// ---------------------------------------------------------------------------
__global__ __launch_bounds__(256, 3) void k2_wfab(
    const float* __restrict__ feat, const f16* __restrict__ pWa,
    const f16* __restrict__ pWb, const float* __restrict__ bfa,
    const float* __restrict__ bfb, f16* __restrict__ h2g, int b0)
{
    __shared__ f16 ftt[800];      // [2][400] feat tile 20x20
    __shared__ f16 hid[20736];    // h1 [324][64] swz
    __shared__ f16 wbufB[64 * 72];// 2-kk weight chunk, row pad 72
    __shared__ float bA[64];
    __shared__ float bB[64];

    const int tid = threadIdx.x;
    const int wid = tid >> 6, lane = tid & 63;
    const int gq = lane >> 4, cl = lane & 15;
    const int x0 = blockIdx.x * 16, y0 = blockIdx.y * 16;
    const int ci = blockIdx.z, b = b0 + ci;

    for (int t = tid; t < 800; t += 256) {
        int cin = t / 400, p = t - 400 * cin;
        int r = p / 20, c = p - 20 * r;
        int gy = y0 - 2 + r, gx = x0 - 2 + c;
        ftt[t] = (f16)(((unsigned)gy < (unsigned)HH && (unsigned)gx < (unsigned)WW)
                           ? feat[((size_t)(b * 2 + cin)) * NPIX + gy * WW + gx] : 0.f);
    }
    if (tid < 64) { bA[tid] = bfa[tid]; bB[tid] = bfb[tid]; }

    int koff[8];
    #pragma unroll
    for (int j = 0; j < 8; j++) {
        int k = gq * 8 + j;
        int kc = k < 18 ? k : 0;
        int cin = kc >= 9 ? 1 : 0;
        int tap = kc - 9 * cin;
        koff[j] = cin * 400 + (tap / 3) * 20 + (tap % 3);
    }

    f16x8 afA[4];
    #pragma unroll
    for (int mt = 0; mt < 4; mt++)
        afA[mt] = *(const f16x8*)&pWa[(mt * 16 + cl) * 32 + gq * 8];
    __syncthreads();

    // wfa: h1 18x18 (static 6-iter unroll)
    #pragma unroll
    for (int it = 0; it < 6; it++) {
        int nt = wid + it * 4;
        if (nt < 21) {
            int p = nt * 16 + cl;
            int pc = p > 323 ? 323 : p;
            int py = pc / 18, px = pc - 18 * py;
            int base = py * 20 + px;
            f16x8 bf;
            #pragma unroll
            for (int j = 0; j < 8; j++) bf[j] = ftt[base + koff[j]];
            int gy = y0 - 1 + py, gx = x0 - 1 + px;
            bool ok = (p < 324) &&
                      ((unsigned)gy < (unsigned)HH && (unsigned)gx < (unsigned)WW);
            #pragma unroll
            for (int mt = 0; mt < 4; mt++) {
                f32x4 z = {0.f, 0.f, 0.f, 0.f};
                f32x4 acc = __builtin_amdgcn_mfma_f32_16x16x32_f16(afA[mt], bf, z, 0, 0, 0);
                if (p < 324) {
                    int c0 = mt * 16 + gq * 4;
                    union { f16 h[4]; uint2 u2; } pk;
                    #pragma unroll
                    for (int r = 0; r < 4; r++)
                        pk.h[r] = (f16)(ok ? fmaxf(acc[r] + bA[c0 + r], 0.f) : 0.f);
                    *(uint2*)&hid[swzoff(p, c0)] = pk.u2;
                }
            }
        }
    }
    __syncthreads();

    // wfb: 9 tap-phases x 2 sub-kks, double-buffered via regs (T14)
    f32x4 acc[4][4];
    #pragma unroll
    for (int i = 0; i < 4; i++)
        #pragma unroll
        for (int mt = 0; mt < 4; mt++) acc[i][mt] = (f32x4){0.f, 0.f, 0.f, 0.f};

    const int wrow = tid >> 3, wcol = (tid & 7) * 8;
    f16x8 wr0 = *(const f16x8*)&pWb[wrow * 576 + wcol];
    f16x8 wr1 = *(const f16x8*)&pWb[(wrow + 32) * 576 + wcol];
    #pragma unroll 1
    for (int t = 0; t < 9; t++) {
        __syncthreads();                         // prev phase's readers done
        *(f16x8*)&wbufB[wrow * 72 + wcol] = wr0;
        *(f16x8*)&wbufB[(wrow + 32) * 72 + wcol] = wr1;
        if (t < 8) {                             // issue next chunk early
            wr0 = *(const f16x8*)&pWb[wrow * 576 + (t + 1) * 64 + wcol];
            wr1 = *(const f16x8*)&pWb[(wrow + 32) * 576 + (t + 1) * 64 + wcol];
        }
        __syncthreads();                         // writes visible
        int u = t / 3, v = t - 3 * u;            // tap = t
        #pragma unroll
        for (int sub = 0; sub < 2; sub++) {
            int c0 = sub * 32 + gq * 8;
            f16x8 af[4];
            #pragma unroll
            for (int mt = 0; mt < 4; mt++)
                af[mt] = *(const f16x8*)&wbufB[(mt * 16 + cl) * 72 + sub * 32 + gq * 8];
            #pragma unroll
            for (int i = 0; i < 4; i++) {
                int nt = wid * 4 + i;
                int hp = (nt + u) * 18 + cl + v;
                f16x8 bf = *(const f16x8*)&hid[swzoff(hp, c0)];
                #pragma unroll
                for (int mt = 0; mt < 4; mt++)
                    acc[i][mt] = __builtin_amdgcn_mfma_f32_16x16x32_f16(af[mt], bf, acc[i][mt], 0, 0, 0);
            }
        }
    }
    #pragma unroll
    for (int i = 0; i < 4; i++) {
        int nt = wid * 4 + i;                       // tile row; pixel col = cl
        size_t pb = ((size_t)ci * NPIX + (size_t)((y0 + nt) * WW + x0 + cl)) * 64;
        #pragma unroll
        for (int mt = 0; mt < 4; mt++) {
            int c0 = mt * 16 + gq * 4;
            union { f16 h[4]; uint2 u2; } pk;
            #pragma unroll
            for (int r = 0; r < 4; r++)
                pk.h[r] = (f16)fmaxf(acc[i][mt][r] + bB[c0 + r], 0.f);
            *(uint2*)&h2g[pb + c0] = pk.u2;
        }
    }
}

// ---------------------------------------------------------------------------
// K3: h2 -> logits(96) -> softmax(81) -> patch apply -> out.
// 1-kk staging kept (51 KB LDS = 3 blocks/CU) + T14 async split. kk loop
// stays unroll 1 (full unroll -> round-5/6 spill; tripwire: WRITE_SIZE ~1MB).
// ---------------------------------------------------------------------------
__global__ __launch_bounds__(256, 3) void k3_wfc_apply(
    const f16* __restrict__ h2g, const f16* __restrict__ pWc,
    const float* __restrict__ bfc, const float* __restrict__ x,
    float* __restrict__ out, int b0)
{
    __shared__ f16 h2t[20736];    // [324][64] swz
    __shared__ f16 wbufC[96 * 36];// per-kk weight chunk, pad 36
    __shared__ float xt24[576];   // 24x24
    __shared__ float bC[96];

    const int tid = threadIdx.x;
    const int wid = tid >> 6, lane = tid & 63;
    const int gq = lane >> 4, cl = lane & 15;
    const int x0 = blockIdx.x * 16, y0 = blockIdx.y * 16;
    const int ci = blockIdx.z, b = b0 + ci;

    for (int t = tid; t < 2592; t += 256) {
        int p = t >> 3, grp = t & 7;
        int py = p / 18, px = p - 18 * py;
        int gy = y0 - 1 + py, gx = x0 - 1 + px;
        f16x8 v = {};
        if ((unsigned)gy < (unsigned)HH && (unsigned)gx < (unsigned)WW)
            v = *(const f16x8*)&h2g[((size_t)ci * NPIX + (size_t)(gy * WW + gx)) * 64 + grp * 8];
        *(f16x8*)&h2t[swzoff(p, grp * 8)] = v;
    }
    const float* xb = x + (size_t)b * NPIX;
    for (int t = tid; t < 576; t += 256) {
        int r = t / 24, c = t - 24 * r;
        int gy = y0 - 4 + r, gx = x0 - 4 + c;
        xt24[t] = ((unsigned)gy < (unsigned)HH && (unsigned)gx < (unsigned)WW)
                      ? xb[gy * WW + gx] : 0.f;
    }
    if (tid < 96) bC[tid] = tid < 81 ? bfc[tid] : 0.f;
    __syncthreads();

    f32x4 acc[4][6];
    #pragma unroll
    for (int i = 0; i < 4; i++)
        #pragma unroll
        for (int mt = 0; mt < 6; mt++) acc[i][mt] = (f32x4){0.f, 0.f, 0.f, 0.f};

    const int crow = tid >> 2, ccol = (tid & 3) * 8;
    f16x8 wr0 = *(const f16x8*)&pWc[crow * 576 + ccol];
    f16x8 wr1 = {};
    if (tid < 128)
        wr1 = *(const f16x8*)&pWc[(crow + 64) * 576 + ccol];
    #pragma unroll 1
    for (int kk = 0; kk < 18; kk++) {
        __syncthreads();                         // prev phase's readers done
        *(f16x8*)&wbufC[crow * 36 + ccol] = wr0;
        if (tid < 128)
            *(f16x8*)&wbufC[(crow + 64) * 36 + ccol] = wr1;
        if (kk < 17) {                           // issue next chunk early
            wr0 = *(const f16x8*)&pWc[crow * 576 + (kk + 1) * 32 + ccol];
            if (tid < 128)
                wr1 = *(const f16x8*)&pWc[(crow + 64) * 576 + (kk + 1) * 32 + ccol];
        }
        __syncthreads();                         // writes visible
        int tap = kk >> 1;
        int u = tap / 3, v = tap - 3 * u;
        int c0 = (kk & 1) * 32 + gq * 8;
        f16x8 af[6];
        #pragma unroll
        for (int mt = 0; mt < 6; mt++)
            af[mt] = *(const f16x8*)&wbufC[(mt * 16 + cl) * 36 + gq * 8];
        #pragma unroll
        for (int i = 0; i < 4; i++) {
            int nt = wid * 4 + i;
            int hp = (nt + u) * 18 + cl + v;
            f16x8 bf = *(const f16x8*)&h2t[swzoff(hp, c0)];
            #pragma unroll
            for (int mt = 0; mt < 6; mt++)
                acc[i][mt] = __builtin_amdgcn_mfma_f32_16x16x32_f16(af[mt], bf, acc[i][mt], 0, 0, 0);
        }
    }

    // softmax over taps (rows) for each pixel (col=cl); reduce across gq lanes
    #pragma unroll
    for (int i = 0; i < 4; i++) {
        int nt = wid * 4 + i;                       // pixel row; pixel col = cl
        float val[6][4];
        float m = -1e30f;
        #pragma unroll
        for (int mt = 0; mt < 6; mt++)
            #pragma unroll
            for (int r = 0; r < 4; r++) {
                int c = mt * 16 + gq * 4 + r;
                float vv = (c <= 80) ? acc[i][mt][r] + bC[c] : -1e30f;
                val[mt][r] = vv;
                m = fmaxf(m, vv);
            }
        m = fmaxf(m, __shfl_xor(m, 16));
        m = fmaxf(m, __shfl_xor(m, 32));
        float s = 0.f, o = 0.f;
        #pragma unroll
        for (int mt = 0; mt < 6; mt++)
            #pragma unroll
            for (int r = 0; r < 4; r++) {
                int c = mt * 16 + gq * 4 + r;
                if (c <= 80) {
                    float e = __expf(val[mt][r] - m);
                    int u9 = c / 9, v9 = c - 9 * u9;
                    s += e;
                    o += e * xt24[(nt + u9) * 24 + cl + v9];
                }
            }
        s += __shfl_xor(s, 16); s += __shfl_xor(s, 32);
        o += __shfl_xor(o, 16); o += __shfl_xor(o, 32);
        if (gq == 0)
            out[(size_t)b * NPIX + (y0 + nt) * WW + x0 + cl] = o / s;
    }
}

// ---------------------------------------------------------------------------
extern "C" void kernel_launch(void* const* d_in, const int* in_sizes, int n_in,
                              void* d_out, int out_size, void* d_ws, size_t ws_size,
                              hipStream_t stream)
{
    const float* x   = (const float*)d_in[0];
    const float* g   = (const float*)d_in[1];
    const float* w1a = (const float*)d_in[2];  const float* b1a = (const float*)d_in[3];
    const float* w1b = (const float*)d_in[4];  const float* b1b = (const float*)d_in[5];
    const float* w2a = (const float*)d_in[6];  const float* b2a = (const float*)d_in[7];
    const float* w2b = (const float*)d_in[8];  const float* b2b = (const float*)d_in[9];
    const float* wfa = (const float*)d_in[10]; const float* bfa = (const float*)d_in[11];
    const float* wfb = (const float*)d_in[12]; const float* bfb = (const float*)d_in[13];
    const float* wfc = (const float*)d_in[14]; const float* bfc = (const float*)d_in[15];
    float* out = (float*)d_out;

    // workspace: feat f32 | h2 chunk f16 | packed weights f16
    float* feat = (float*)d_ws;                       // 2,097,152 f32
    size_t featB = 2097152ull * 4;
    size_t pkB = 100352ull * 2;
    int nbc = 16;
    while (nbc > 1 && featB + (size_t)nbc * NPIX * 64 * 2 + pkB > ws_size) nbc >>= 1;

    f16* h2g = (f16*)((char*)d_ws + featB);
    f16* pk  = h2g + (size_t)nbc * NPIX * 64;
    f16* pA1  = pk;             // 2048
    f16* pA2  = pA1 + 2048;     // 2048
    f16* pWa  = pA2 + 2048;     // 2048
    f16* pBs1 = pWa + 2048;     // 1024
    f16* pBs2 = pBs1 + 1024;    // 1024
    f16* pWb  = pBs2 + 1024;    // 36864
    f16* pWc  = pWb + 36864;    // 55296

    prepack_kernel<<<dim3(216), 256, 0, stream>>>(
        w1a, w2a, w1b, w2b, wfa, wfb, wfc, pA1, pA2, pWa, pBs1, pBs2, pWb, pWc);

    k1_branch<<<dim3(16, 16, 32), 256, 0, stream>>>(
        x, g, b1a, b2a, b1b, b2b, pA1, pA2, pBs1, pBs2, feat);

    for (int b0 = 0; b0 < NB; b0 += nbc) {
        int cn = (NB - b0) < nbc ? (NB - b0) : nbc;
        k2_wfab<<<dim3(16, 16, cn), 256, 0, stream>>>(
            feat, pWa, pWb, bfa, bfb, h2g, b0);
        k3_wfc_apply<<<dim3(16, 16, cn), 256, 0, stream>>>(
            h2g, pWc, bfc, x, out, b0);
    }
}